// Round 3
// baseline (595.106 us; speedup 1.0000x reference)
//
#include <hip/hip_runtime.h>

typedef __attribute__((ext_vector_type(8))) short s16x8;
typedef __attribute__((ext_vector_type(4))) float f32x4;
typedef unsigned short u16;
typedef unsigned char u8;

#define D_FEAT 128

__device__ __forceinline__ float bf2f(u16 b) {
    unsigned u = ((unsigned)b) << 16;
    return __builtin_bit_cast(float, u);
}
__device__ __forceinline__ u16 f2bf(float f) {
    unsigned u = __builtin_bit_cast(unsigned, f);
    u = u + 0x7fffu + ((u >> 16) & 1u);   // RNE
    return (u16)(u >> 16);
}

// ---------------- dtype sniff: 0 = bf16, 1 = fp32 ----------------
// bf16 N(0,1) data: every u16 has exponent in [100,140] (≈always).
// fp32 data: even u16 indices are low mantissa halves -> ~uniform -> ~16% sane.
__global__ void sniff_kernel(const void* __restrict__ x, int* __restrict__ flag) {
    const u16* p = (const u16*)x;
    int sane = 0;
    for (int i = 0; i < 64; ++i) {
        u16 w = p[2 * i];
        int e = (w >> 7) & 0xFF;
        sane += (e >= 100 && e <= 140) ? 1 : 0;
    }
    *flag = (sane >= 40) ? 0 : 1;
}

// ---------------- CSR build (dtype-free) ----------------
__global__ __launch_bounds__(256) void zero_kernel(int* __restrict__ p, int n) {
    int i = blockIdx.x * 256 + threadIdx.x;
    if (i < n) p[i] = 0;
}

__global__ __launch_bounds__(256) void count_kernel(const int* __restrict__ dst,
                                                    int* __restrict__ counts, int E) {
    int e = blockIdx.x * 256 + threadIdx.x;
    if (e < E) atomicAdd(&counts[dst[e]], 1);
}

__global__ __launch_bounds__(1024) void scan_kernel(const int* __restrict__ counts,
                                                    int* __restrict__ row_start, int n) {
    __shared__ int wsum[16];
    const int tid = threadIdx.x;
    const int lane = tid & 63, wid = tid >> 6;
    int base = 0;
    if (tid == 0) row_start[0] = 0;
    for (int start = 0; start < n; start += 1024) {
        int i = start + tid;
        int v = (i < n) ? counts[i] : 0;
        int s = v;
        #pragma unroll
        for (int off = 1; off < 64; off <<= 1) {
            int t = __shfl_up(s, off, 64);
            if (lane >= off) s += t;
        }
        if (lane == 63) wsum[wid] = s;
        __syncthreads();
        if (wid == 0) {
            int wv = (lane < 16) ? wsum[lane] : 0;
            int ss = wv;
            #pragma unroll
            for (int off = 1; off < 16; off <<= 1) {
                int t = __shfl_up(ss, off, 64);
                if (lane >= off) ss += t;
            }
            if (lane < 16) wsum[lane] = ss;
        }
        __syncthreads();
        int wave_off = (wid == 0) ? 0 : wsum[wid - 1];
        if (i < n) row_start[i + 1] = base + wave_off + s;
        base += wsum[15];
        __syncthreads();
    }
}

__global__ __launch_bounds__(256) void cursor_init_kernel(const int* __restrict__ row_start,
                                                          int* __restrict__ cursor, int n) {
    int i = blockIdx.x * 256 + threadIdx.x;
    if (i < n) cursor[i] = row_start[i];
}

__global__ __launch_bounds__(256) void scatter_kernel(const int* __restrict__ src,
                                                      const int* __restrict__ dst,
                                                      const int* __restrict__ eattr,
                                                      int* __restrict__ cursor,
                                                      u16* __restrict__ esrc,
                                                      u8* __restrict__ ecode, int E) {
    int e = blockIdx.x * 256 + threadIdx.x;
    if (e < E) {
        int s = src[e];
        int code = eattr[2 * e] * 3 + eattr[2 * e + 1];
        int pos = atomicAdd(&cursor[dst[e]], 1);
        esrc[pos] = (u16)s;
        ecode[pos] = (u8)code;
    }
}

// ---------------- weight prep: always outputs bf16 ----------------
template <int DT>
__global__ __launch_bounds__(256) void transpose_kernel(const void* __restrict__ W1_0,
                                                        const void* __restrict__ W2_0,
                                                        const void* __restrict__ W1_1,
                                                        const void* __restrict__ W2_1,
                                                        u16* __restrict__ out,
                                                        const int* __restrict__ flag) {
    if (*flag != DT) return;
    int mat = blockIdx.y;
    const void* s = (mat == 0) ? W1_0 : (mat == 1) ? W2_0 : (mat == 2) ? W1_1 : W2_1;
    int K = (mat & 1) ? 256 : 128;
    int Nc = 384 - K;
    u16* d = out + mat * 32768;
    int idx = blockIdx.x * 256 + threadIdx.x;
    int n = idx / K, k = idx - n * K;
    if (DT == 0) d[idx] = ((const u16*)s)[k * Nc + n];
    else         d[idx] = f2bf(((const float*)s)[k * Nc + n]);
}

template <int DT>
__global__ __launch_bounds__(128) void emb_kernel(const void* __restrict__ ee1_0,
                                                  const void* __restrict__ ee2_0,
                                                  const void* __restrict__ ee1_1,
                                                  const void* __restrict__ ee2_1,
                                                  float* __restrict__ emb,
                                                  const int* __restrict__ flag) {
    if (*flag != DT) return;
    int code = blockIdx.x;
    int layer = blockIdx.y;
    int d = threadIdx.x;
    int a0 = code / 3, a1 = code - a0 * 3;
    const void* e1 = layer ? ee1_1 : ee1_0;
    const void* e2 = layer ? ee2_1 : ee2_0;
    float v;
    if (DT == 0) v = bf2f(((const u16*)e1)[a0 * 128 + d]) + bf2f(((const u16*)e2)[a1 * 128 + d]);
    else         v = ((const float*)e1)[a0 * 128 + d] + ((const float*)e2)[a1 * 128 + d];
    emb[layer * 18 * 128 + code * 128 + d] = v;
}

// ---------------- aggregation: one wave per node, 4 nodes/block ----------------
// XDT: dtype of X. Output A always bf16. expect<0 -> unguarded.
template <int XDT>
__global__ __launch_bounds__(256) void aggregate_kernel(const void* __restrict__ X,
                                                        const int* __restrict__ row_start,
                                                        const u16* __restrict__ esrc,
                                                        const u8* __restrict__ ecode,
                                                        const float* __restrict__ emb,
                                                        u16* __restrict__ A, int N,
                                                        const int* __restrict__ flag, int expect) {
    if (expect >= 0 && *flag != expect) return;
    __shared__ float semb[18 * 128];
    for (int i = threadIdx.x; i < 18 * 128; i += 256) semb[i] = emb[i];
    __syncthreads();
    int node = blockIdx.x * 4 + (threadIdx.x >> 6);
    int lane = threadIdx.x & 63;
    if (node >= N) return;
    int s = row_start[node], e = row_start[node + 1];
    const float2* sem2 = (const float2*)semb;
    float a0 = 0.f, a1 = 0.f;
    for (int i = s; i < e; ++i) {
        int src = esrc[i];
        int code = ecode[i];
        float2 ev = sem2[code * 64 + lane];
        if (XDT == 0) {
            unsigned xv = *(const unsigned*)((const u16*)X + src * D_FEAT + lane * 2);
            a0 += __builtin_bit_cast(float, xv << 16) + ev.x;
            a1 += __builtin_bit_cast(float, xv & 0xFFFF0000u) + ev.y;
        } else {
            float2 xv = *(const float2*)((const float*)X + src * D_FEAT + lane * 2);
            a0 += xv.x + ev.x;
            a1 += xv.y + ev.y;
        }
    }
    unsigned out = (unsigned)f2bf(a0) | ((unsigned)f2bf(a1) << 16);
    *(unsigned*)(A + node * D_FEAT + lane * 2) = out;
}

// ---------------- fused MLP ----------------
// A: [M,128] bf16. Bt weights bf16. bias dtype = DT. Output dtype = ODT.
#define HPAD 264
template <int DT, int ODT, bool RELU2>
__global__ __launch_bounds__(256) void mlp_kernel(const u16* __restrict__ A,
                                                  const u16* __restrict__ B1t,
                                                  const void* __restrict__ bias1,
                                                  const u16* __restrict__ B2t,
                                                  const void* __restrict__ bias2,
                                                  void* __restrict__ C, int M,
                                                  const int* __restrict__ flag, int expect) {
    if (expect >= 0 && *flag != expect) return;
    __shared__ __align__(16) u16 hh[4][16][HPAD];
    const int tid = threadIdx.x;
    const int wave = tid >> 6;
    const int lane = tid & 63;
    const int m16 = lane & 15;
    const int quad = lane >> 4;

    const int row0 = blockIdx.x * 64 + wave * 16;
    const int arow = row0 + m16;
    const bool avalid = arow < M;

    // gemm1: h[16x256] = relu(A[16x128] @ W1 + b1)
    f32x4 acc[16];
    #pragma unroll
    for (int t = 0; t < 16; ++t) acc[t] = f32x4{0, 0, 0, 0};

    #pragma unroll
    for (int kb = 0; kb < 128; kb += 32) {
        s16x8 afrag = {};
        if (avalid) afrag = *(const s16x8*)(A + arow * 128 + kb + quad * 8);
        #pragma unroll
        for (int t = 0; t < 16; ++t) {
            s16x8 bfrag = *(const s16x8*)(B1t + (t * 16 + m16) * 128 + kb + quad * 8);
            acc[t] = __builtin_amdgcn_mfma_f32_16x16x32_bf16(afrag, bfrag, acc[t], 0, 0, 0);
        }
    }

    #pragma unroll
    for (int t = 0; t < 16; ++t) {
        const int col = t * 16 + m16;
        const float bv = (DT == 0) ? bf2f(((const u16*)bias1)[col]) : ((const float*)bias1)[col];
        #pragma unroll
        for (int r = 0; r < 4; ++r) {
            float v = acc[t][r] + bv;
            v = v > 0.f ? v : 0.f;
            hh[wave][quad * 4 + r][col] = f2bf(v);
        }
    }
    __syncthreads();

    // gemm2: out[16x128] = h[16x256] @ W2 + b2 (opt relu)
    f32x4 acc2[8];
    #pragma unroll
    for (int t = 0; t < 8; ++t) acc2[t] = f32x4{0, 0, 0, 0};

    #pragma unroll
    for (int kb = 0; kb < 256; kb += 32) {
        s16x8 afrag = *(const s16x8*)(&hh[wave][m16][kb + quad * 8]);
        #pragma unroll
        for (int t = 0; t < 8; ++t) {
            s16x8 bfrag = *(const s16x8*)(B2t + (t * 16 + m16) * 256 + kb + quad * 8);
            acc2[t] = __builtin_amdgcn_mfma_f32_16x16x32_bf16(afrag, bfrag, acc2[t], 0, 0, 0);
        }
    }

    #pragma unroll
    for (int t = 0; t < 8; ++t) {
        const int col = t * 16 + m16;
        const float bv = (DT == 0) ? bf2f(((const u16*)bias2)[col]) : ((const float*)bias2)[col];
        #pragma unroll
        for (int r = 0; r < 4; ++r) {
            const int row = row0 + quad * 4 + r;
            if (row < M) {
                float v = acc2[t][r] + bv;
                if (RELU2) v = v > 0.f ? v : 0.f;
                if (ODT == 0) ((u16*)C)[row * 128 + col] = f2bf(v);
                else          ((float*)C)[row * 128 + col] = v;
            }
        }
    }
}

extern "C" void kernel_launch(void* const* d_in, const int* in_sizes, int n_in,
                              void* d_out, int out_size, void* d_ws, size_t ws_size,
                              hipStream_t stream) {
    const int N = in_sizes[0] / D_FEAT;     // 50000
    const int E = in_sizes[1] / 2;          // 800000

    const void* x     = d_in[0];
    const int* eidx   = (const int*)d_in[1];
    const int* eattr  = (const int*)d_in[2];
    const void* ee1_0 = d_in[3];
    const void* ee2_0 = d_in[4];
    const void* W1_0  = d_in[5];
    const void* b1_0  = d_in[6];
    const void* W2_0  = d_in[7];
    const void* b2_0  = d_in[8];
    const void* ee1_1 = d_in[9];
    const void* ee2_1 = d_in[10];
    const void* W1_1  = d_in[11];
    const void* b1_1  = d_in[12];
    const void* W2_1  = d_in[13];
    const void* b2_1  = d_in[14];

    // workspace layout: total ~15.88 MB
    char* ws = (char*)d_ws;
    size_t off = 0;
    auto alloc = [&](size_t bytes) { size_t o = off; off = (off + bytes + 255) & ~(size_t)255; return o; };
    size_t o_flag     = alloc(4);
    size_t o_rowstart = alloc((size_t)(N + 1) * 4);
    size_t o_cursor   = alloc((size_t)N * 4);
    size_t o_esrc     = alloc((size_t)E * 2);
    size_t o_ecode    = alloc((size_t)E);
    size_t o_emb      = alloc(2 * 18 * 128 * 4);
    size_t o_wt       = alloc(4 * 32768 * 2);
    size_t o_aa       = alloc((size_t)N * D_FEAT * 2);

    int*   flag      = (int*)(ws + o_flag);
    int*   row_start = (int*)(ws + o_rowstart);
    int*   cursor    = (int*)(ws + o_cursor);
    u16*   esrc      = (u16*)(ws + o_esrc);
    u8*    ecode     = (u8*)(ws + o_ecode);
    float* emb       = (float*)(ws + o_emb);
    u16*   W1t_0     = (u16*)(ws + o_wt);
    u16*   W2t_0     = W1t_0 + 32768;
    u16*   W1t_1     = W2t_0 + 32768;
    u16*   W2t_1     = W1t_1 + 32768;
    u16*   AA        = (u16*)(ws + o_aa);      // node-feature scratch, bf16
    u16*   X2        = (u16*)d_out;            // layer-0 output (bf16), front of d_out

    const int Eb = (E + 255) / 256;
    const int Nb = (N + 255) / 256;
    const int rows64 = (N + 63) / 64;          // 782
    const int aggB = (N + 3) / 4;

    // dtype sniff
    sniff_kernel<<<1, 1, 0, stream>>>(x, flag);

    // CSR build (dtype-free)
    zero_kernel<<<Nb, 256, 0, stream>>>(cursor, N);
    count_kernel<<<Eb, 256, 0, stream>>>(eidx + E, cursor, E);
    scan_kernel<<<1, 1024, 0, stream>>>(cursor, row_start, N);
    cursor_init_kernel<<<Nb, 256, 0, stream>>>(row_start, cursor, N);
    scatter_kernel<<<Eb, 256, 0, stream>>>(eidx, eidx + E, eattr, cursor, esrc, ecode, E);

    // prep (guarded per dtype)
    emb_kernel<0><<<dim3(18, 2), 128, 0, stream>>>(ee1_0, ee2_0, ee1_1, ee2_1, emb, flag);
    emb_kernel<1><<<dim3(18, 2), 128, 0, stream>>>(ee1_0, ee2_0, ee1_1, ee2_1, emb, flag);
    transpose_kernel<0><<<dim3(128, 4), 256, 0, stream>>>(W1_0, W2_0, W1_1, W2_1, W1t_0, flag);
    transpose_kernel<1><<<dim3(128, 4), 256, 0, stream>>>(W1_0, W2_0, W1_1, W2_1, W1t_0, flag);

    // layer 0: x -> AA -> X2(d_out front, bf16)
    aggregate_kernel<0><<<aggB, 256, 0, stream>>>(x, row_start, esrc, ecode, emb, AA, N, flag, 0);
    aggregate_kernel<1><<<aggB, 256, 0, stream>>>(x, row_start, esrc, ecode, emb, AA, N, flag, 1);
    mlp_kernel<0, 0, true><<<rows64, 256, 0, stream>>>(AA, W1t_0, b1_0, W2t_0, b2_0, X2, N, flag, 0);
    mlp_kernel<1, 0, true><<<rows64, 256, 0, stream>>>(AA, W1t_0, b1_0, W2t_0, b2_0, X2, N, flag, 1);

    // layer 1: X2 -> AA -> d_out (true dtype)
    aggregate_kernel<0><<<aggB, 256, 0, stream>>>(X2, row_start, esrc, ecode, emb + 18 * 128, AA, N, flag, -1);
    mlp_kernel<0, 0, false><<<rows64, 256, 0, stream>>>(AA, W1t_1, b1_1, W2t_1, b2_1, d_out, N, flag, 0);
    mlp_kernel<1, 1, false><<<rows64, 256, 0, stream>>>(AA, W1t_1, b1_1, W2t_1, b2_1, d_out, N, flag, 1);
}

// Round 7
// 458.123 us; speedup vs baseline: 1.2990x; 1.2990x over previous
//
#include <hip/hip_runtime.h>

typedef __attribute__((ext_vector_type(8))) short s16x8;
typedef __attribute__((ext_vector_type(4))) float f32x4;
typedef unsigned short u16;
typedef unsigned char u8;

#define D_FEAT 128

__device__ __forceinline__ u16 f2bf(float f) {
    unsigned u = __builtin_bit_cast(unsigned, f);
    u = u + 0x7fffu + ((u >> 16) & 1u);   // RNE
    return (u16)(u >> 16);
}

// ---------------- x (fp32) -> bf16 ----------------
__global__ __launch_bounds__(256) void tobf16_kernel(const float4* __restrict__ X,
                                                     u16* __restrict__ out, int n4) {
    int i = blockIdx.x * 256 + threadIdx.x;
    if (i < n4) {
        float4 v = X[i];
        uint2 p;
        p.x = (unsigned)f2bf(v.x) | ((unsigned)f2bf(v.y) << 16);
        p.y = (unsigned)f2bf(v.z) | ((unsigned)f2bf(v.w) << 16);
        *(uint2*)(out + (size_t)i * 4) = p;
    }
}

// ---------------- CSR build ----------------
__global__ __launch_bounds__(256) void zero_kernel(int* __restrict__ p, int n) {
    int i = blockIdx.x * 256 + threadIdx.x;
    if (i < n) p[i] = 0;
}

__global__ __launch_bounds__(256) void count_kernel(const int* __restrict__ dst,
                                                    int* __restrict__ counts, int E) {
    int e = blockIdx.x * 256 + threadIdx.x;
    if (e < E) atomicAdd(&counts[dst[e]], 1);
}

// pass A: per-block inclusive scan of counts -> row_start[i+1]; block totals -> bsum
__global__ __launch_bounds__(256) void scanA_kernel(const int* __restrict__ counts,
                                                    int* __restrict__ row_start,
                                                    int* __restrict__ bsum, int n) {
    __shared__ int wt[4];
    const int t = threadIdx.x, lane = t & 63, wid = t >> 6;
    const int i = blockIdx.x * 256 + t;
    int v = (i < n) ? counts[i] : 0;
    int s = v;
    #pragma unroll
    for (int off = 1; off < 64; off <<= 1) {
        int u = __shfl_up(s, off, 64);
        if (lane >= off) s += u;
    }
    if (lane == 63) wt[wid] = s;
    __syncthreads();
    int add = 0;
    #pragma unroll
    for (int w = 0; w < 4; ++w) add += (w < wid) ? wt[w] : 0;
    s += add;
    if (i < n) row_start[i + 1] = s;
    if (t == 255) bsum[blockIdx.x] = s;
}

// pass B: single block scans bsum[0..m) -> exclusive offsets bsum2 (m <= 256)
__global__ __launch_bounds__(256) void scanB_kernel(const int* __restrict__ bsum,
                                                    int* __restrict__ bsum2, int m) {
    __shared__ int wt[4];
    const int t = threadIdx.x, lane = t & 63, wid = t >> 6;
    int v = (t < m) ? bsum[t] : 0;
    int s = v;
    #pragma unroll
    for (int off = 1; off < 64; off <<= 1) {
        int u = __shfl_up(s, off, 64);
        if (lane >= off) s += u;
    }
    if (lane == 63) wt[wid] = s;
    __syncthreads();
    int add = 0;
    #pragma unroll
    for (int w = 0; w < 4; ++w) add += (w < wid) ? wt[w] : 0;
    s += add;
    if (t < m) bsum2[t] = s - v;   // exclusive
}

// pass C: add block offsets; also fill cursor[i] = row_start[i]
__global__ __launch_bounds__(256) void scanC_kernel(int* __restrict__ row_start,
                                                    int* __restrict__ cursor,
                                                    const int* __restrict__ bsum2, int n) {
    const int i = blockIdx.x * 256 + threadIdx.x;
    if (i == 0) { row_start[0] = 0; cursor[0] = 0; }
    if (i < n) {
        int val = row_start[i + 1] + bsum2[blockIdx.x];
        row_start[i + 1] = val;
        if (i + 1 < n) cursor[i + 1] = val;
    }
}

__global__ __launch_bounds__(256) void scatter_kernel(const int* __restrict__ src,
                                                      const int* __restrict__ dst,
                                                      const int* __restrict__ eattr,
                                                      int* __restrict__ cursor,
                                                      u16* __restrict__ esrc,
                                                      u8* __restrict__ ecode, int E) {
    int e = blockIdx.x * 256 + threadIdx.x;
    if (e < E) {
        int s = src[e];
        int code = eattr[2 * e] * 3 + eattr[2 * e + 1];
        int pos = atomicAdd(&cursor[dst[e]], 1);
        esrc[pos] = (u16)s;
        ecode[pos] = (u8)code;
    }
}

// ---------------- weight prep: fp32 in -> transposed bf16 out ----------------
// out: [W1t_0 256x128][W2t_0 128x256][W1t_1 256x128][W2t_1 128x256]
__global__ __launch_bounds__(256) void transpose_kernel(const float* __restrict__ W1_0,
                                                        const float* __restrict__ W2_0,
                                                        const float* __restrict__ W1_1,
                                                        const float* __restrict__ W2_1,
                                                        u16* __restrict__ out) {
    int mat = blockIdx.y;
    const float* s = (mat == 0) ? W1_0 : (mat == 1) ? W2_0 : (mat == 2) ? W1_1 : W2_1;
    int K = (mat & 1) ? 256 : 128;   // Bt row length
    int Nc = 384 - K;
    u16* d = out + mat * 32768;
    int idx = blockIdx.x * 256 + threadIdx.x;  // idx = n*K + k
    int n = idx / K, k = idx - n * K;
    d[idx] = f2bf(s[k * Nc + n]);
}

// emb[layer][code*128+d] = ee1[code/3][d] + ee2[code%3][d]  (fp32)
__global__ __launch_bounds__(128) void emb_kernel(const float* __restrict__ ee1_0,
                                                  const float* __restrict__ ee2_0,
                                                  const float* __restrict__ ee1_1,
                                                  const float* __restrict__ ee2_1,
                                                  float* __restrict__ emb) {
    int code = blockIdx.x;
    int layer = blockIdx.y;
    int d = threadIdx.x;
    int a0 = code / 3, a1 = code - a0 * 3;
    const float* e1 = layer ? ee1_1 : ee1_0;
    const float* e2 = layer ? ee2_1 : ee2_0;
    emb[layer * 18 * 128 + code * 128 + d] = e1[a0 * 128 + d] + e2[a1 * 128 + d];
}

// ---------------- aggregation: one wave per node, 8-way batched bf16 gather ----------------
__global__ __launch_bounds__(256) void aggregate_kernel(const u16* __restrict__ X,
                                                        const int* __restrict__ row_start,
                                                        const u16* __restrict__ esrc,
                                                        const u8* __restrict__ ecode,
                                                        const float* __restrict__ emb,
                                                        u16* __restrict__ A, int N) {
    __shared__ float semb[18 * 128];
    for (int i = threadIdx.x; i < 18 * 128; i += 256) semb[i] = emb[i];
    __syncthreads();
    const int node = blockIdx.x * 4 + (threadIdx.x >> 6);
    const int lane = threadIdx.x & 63;
    if (node >= N) return;
    const int s = row_start[node], e = row_start[node + 1];
    const float2* sem2 = (const float2*)semb;
    const u16* xl = X + lane * 2;       // lane-fixed column offset
    float a0 = 0.f, a1 = 0.f;
    int i = s;
    for (; i + 8 <= e; i += 8) {
        unsigned xv[8];
        float2 ev[8];
        #pragma unroll
        for (int j = 0; j < 8; ++j) {
            int src = esrc[i + j];
            xv[j] = *(const unsigned*)(xl + src * D_FEAT);
        }
        #pragma unroll
        for (int j = 0; j < 8; ++j) ev[j] = sem2[(int)ecode[i + j] * 64 + lane];
        #pragma unroll
        for (int j = 0; j < 8; ++j) {
            a0 += __builtin_bit_cast(float, xv[j] << 16) + ev[j].x;
            a1 += __builtin_bit_cast(float, xv[j] & 0xFFFF0000u) + ev[j].y;
        }
    }
    for (; i < e; ++i) {
        int src = esrc[i];
        unsigned xv = *(const unsigned*)(xl + src * D_FEAT);
        float2 ev = sem2[(int)ecode[i] * 64 + lane];
        a0 += __builtin_bit_cast(float, xv << 16) + ev.x;
        a1 += __builtin_bit_cast(float, xv & 0xFFFF0000u) + ev.y;
    }
    unsigned out = (unsigned)f2bf(a0) | ((unsigned)f2bf(a1) << 16);
    *(unsigned*)(A + node * D_FEAT + lane * 2) = out;
}

// ---------------- fused MLP: C = relu?(relu(A @ W1 + b1) @ W2 + b2) ----------------
// A bf16 [M,128]; B1t/B2t bf16; biases fp32; out bf16 (u16) or fp32 per OUTF32.
#define HPAD 264
template <bool RELU2, bool OUTF32>
__global__ __launch_bounds__(256) void mlp_kernel(const u16* __restrict__ A,
                                                  const u16* __restrict__ B1t,
                                                  const float* __restrict__ bias1,
                                                  const u16* __restrict__ B2t,
                                                  const float* __restrict__ bias2,
                                                  void* __restrict__ C, int M) {
    __shared__ __align__(16) u16 hh[4][16][HPAD];
    const int tid = threadIdx.x;
    const int wave = tid >> 6;
    const int lane = tid & 63;
    const int m16 = lane & 15;
    const int quad = lane >> 4;

    const int row0 = blockIdx.x * 64 + wave * 16;
    const int arow = row0 + m16;
    const bool avalid = arow < M;

    // gemm1: h[16x256] = relu(A[16x128] @ W1 + b1)
    f32x4 acc[16];
    #pragma unroll
    for (int t = 0; t < 16; ++t) acc[t] = f32x4{0, 0, 0, 0};

    #pragma unroll
    for (int kb = 0; kb < 128; kb += 32) {
        s16x8 afrag = {};
        if (avalid) afrag = *(const s16x8*)(A + arow * 128 + kb + quad * 8);
        #pragma unroll
        for (int t = 0; t < 16; ++t) {
            s16x8 bfrag = *(const s16x8*)(B1t + (t * 16 + m16) * 128 + kb + quad * 8);
            acc[t] = __builtin_amdgcn_mfma_f32_16x16x32_bf16(afrag, bfrag, acc[t], 0, 0, 0);
        }
    }

    #pragma unroll
    for (int t = 0; t < 16; ++t) {
        const int col = t * 16 + m16;
        const float bv = bias1[col];
        #pragma unroll
        for (int r = 0; r < 4; ++r) {
            float v = acc[t][r] + bv;
            v = v > 0.f ? v : 0.f;
            hh[wave][quad * 4 + r][col] = f2bf(v);
        }
    }
    __syncthreads();

    // gemm2: out[16x128] = h[16x256] @ W2 + b2 (opt relu)
    f32x4 acc2[8];
    #pragma unroll
    for (int t = 0; t < 8; ++t) acc2[t] = f32x4{0, 0, 0, 0};

    #pragma unroll
    for (int kb = 0; kb < 256; kb += 32) {
        s16x8 afrag = *(const s16x8*)(&hh[wave][m16][kb + quad * 8]);
        #pragma unroll
        for (int t = 0; t < 8; ++t) {
            s16x8 bfrag = *(const s16x8*)(B2t + (t * 16 + m16) * 256 + kb + quad * 8);
            acc2[t] = __builtin_amdgcn_mfma_f32_16x16x32_bf16(afrag, bfrag, acc2[t], 0, 0, 0);
        }
    }

    #pragma unroll
    for (int t = 0; t < 8; ++t) {
        const int col = t * 16 + m16;
        const float bv = bias2[col];
        #pragma unroll
        for (int r = 0; r < 4; ++r) {
            const int row = row0 + quad * 4 + r;
            if (row < M) {
                float v = acc2[t][r] + bv;
                if (RELU2) v = v > 0.f ? v : 0.f;
                if (OUTF32) ((float*)C)[row * 128 + col] = v;
                else        ((u16*)C)[row * 128 + col] = f2bf(v);
            }
        }
    }
}

extern "C" void kernel_launch(void* const* d_in, const int* in_sizes, int n_in,
                              void* d_out, int out_size, void* d_ws, size_t ws_size,
                              hipStream_t stream) {
    const int N = in_sizes[0] / D_FEAT;     // 50000
    const int E = in_sizes[1] / 2;          // 800000

    const float* x    = (const float*)d_in[0];
    const int* eidx   = (const int*)d_in[1];   // [2,E]: src at [0,E), dst at [E,2E)
    const int* eattr  = (const int*)d_in[2];   // [E,2]
    const float* ee1_0 = (const float*)d_in[3];
    const float* ee2_0 = (const float*)d_in[4];
    const float* W1_0  = (const float*)d_in[5];
    const float* b1_0  = (const float*)d_in[6];
    const float* W2_0  = (const float*)d_in[7];
    const float* b2_0  = (const float*)d_in[8];
    const float* ee1_1 = (const float*)d_in[9];
    const float* ee2_1 = (const float*)d_in[10];
    const float* W1_1  = (const float*)d_in[11];
    const float* b1_1  = (const float*)d_in[12];
    const float* W2_1  = (const float*)d_in[13];
    const float* b2_1  = (const float*)d_in[14];

    // workspace (~15.88 MB, within the round-3-proven budget)
    char* ws = (char*)d_ws;
    size_t off = 0;
    auto alloc = [&](size_t bytes) { size_t o = off; off = (off + bytes + 255) & ~(size_t)255; return o; };
    size_t o_rowstart = alloc((size_t)(N + 1) * 4);
    size_t o_cursor   = alloc((size_t)N * 4);
    size_t o_esrc     = alloc((size_t)E * 2);
    size_t o_ecode    = alloc((size_t)E);
    size_t o_bsum     = alloc(1024);
    size_t o_bsum2    = alloc(1024);
    size_t o_emb      = alloc(2 * 18 * 128 * 4);
    size_t o_wt       = alloc(4 * 32768 * 2);
    size_t o_aa       = alloc((size_t)N * D_FEAT * 2);

    int*   row_start = (int*)(ws + o_rowstart);
    int*   cursor    = (int*)(ws + o_cursor);     // doubles as counts
    u16*   esrc      = (u16*)(ws + o_esrc);
    u8*    ecode     = (u8*)(ws + o_ecode);
    int*   bsum      = (int*)(ws + o_bsum);
    int*   bsum2     = (int*)(ws + o_bsum2);
    float* emb       = (float*)(ws + o_emb);
    u16*   W1t_0     = (u16*)(ws + o_wt);
    u16*   W2t_0     = W1t_0 + 32768;
    u16*   W1t_1     = W2t_0 + 32768;
    u16*   W2t_1     = W1t_1 + 32768;
    u16*   AA        = (u16*)(ws + o_aa);         // aggregated features, bf16

    // d_out (fp32, 25.6 MB) doubles as staging:
    //   front 12.8 MB: X2 = bf16 layer-0 output (dead after layer-1 aggregate)
    //   back  12.8 MB: xb = bf16 copy of x      (dead after layer-0 aggregate)
    // final mlp overwrites all 25.6 MB with fp32 output.
    u16* X2 = (u16*)d_out;
    u16* xb = (u16*)d_out + (size_t)N * D_FEAT;

    const int Eb = (E + 255) / 256;
    const int Nb = (N + 255) / 256;               // 196
    const int rows64 = (N + 63) / 64;             // 782
    const int aggB = (N + 3) / 4;
    const int n4 = N * D_FEAT / 4;

    // x -> bf16 (parked in back half of d_out)
    tobf16_kernel<<<(n4 + 255) / 256, 256, 0, stream>>>((const float4*)x, xb, n4);

    // CSR build
    zero_kernel<<<Nb, 256, 0, stream>>>(cursor, N);
    count_kernel<<<Eb, 256, 0, stream>>>(eidx + E, cursor, E);
    scanA_kernel<<<Nb, 256, 0, stream>>>(cursor, row_start, bsum, N);
    scanB_kernel<<<1, 256, 0, stream>>>(bsum, bsum2, Nb);
    scanC_kernel<<<Nb, 256, 0, stream>>>(row_start, cursor, bsum2, N);
    scatter_kernel<<<Eb, 256, 0, stream>>>(eidx, eidx + E, eattr, cursor, esrc, ecode, E);

    // prep
    emb_kernel<<<dim3(18, 2), 128, 0, stream>>>(ee1_0, ee2_0, ee1_1, ee2_1, emb);
    transpose_kernel<<<dim3(128, 4), 256, 0, stream>>>(W1_0, W2_0, W1_1, W2_1, W1t_0);

    // layer 0: xb -> AA -> X2 (bf16, front of d_out)
    aggregate_kernel<<<aggB, 256, 0, stream>>>(xb, row_start, esrc, ecode, emb, AA, N);
    mlp_kernel<true, false><<<rows64, 256, 0, stream>>>(AA, W1t_0, b1_0, W2t_0, b2_0, X2, N);

    // layer 1: X2 -> AA -> d_out (fp32)
    aggregate_kernel<<<aggB, 256, 0, stream>>>(X2, row_start, esrc, ecode, emb + 18 * 128, AA, N);
    mlp_kernel<false, true><<<rows64, 256, 0, stream>>>(AA, W1t_1, b1_1, W2t_1, b2_1, d_out, N);
}

// Round 8
// 394.806 us; speedup vs baseline: 1.5073x; 1.1604x over previous
//
#include <hip/hip_runtime.h>

typedef __attribute__((ext_vector_type(8))) short s16x8;
typedef __attribute__((ext_vector_type(4))) float f32x4;
typedef unsigned short u16;
typedef unsigned char u8;

#define D_FEAT 128

__device__ __forceinline__ u16 f2bf(float f) {
    unsigned u = __builtin_bit_cast(unsigned, f);
    u = u + 0x7fffu + ((u >> 16) & 1u);   // RNE
    return (u16)(u >> 16);
}

// ---------------- x (fp32) -> bf16 ----------------
__global__ __launch_bounds__(256) void tobf16_kernel(const float4* __restrict__ X,
                                                     u16* __restrict__ out, int n4) {
    int i = blockIdx.x * 256 + threadIdx.x;
    if (i < n4) {
        float4 v = X[i];
        uint2 p;
        p.x = (unsigned)f2bf(v.x) | ((unsigned)f2bf(v.y) << 16);
        p.y = (unsigned)f2bf(v.z) | ((unsigned)f2bf(v.w) << 16);
        *(uint2*)(out + (size_t)i * 4) = p;
    }
}

// ---------------- CSR build ----------------
__global__ __launch_bounds__(256) void zero_kernel(int* __restrict__ p, int n) {
    int i = blockIdx.x * 256 + threadIdx.x;
    if (i < n) p[i] = 0;
}

__global__ __launch_bounds__(256) void count_kernel(const int* __restrict__ dst,
                                                    int* __restrict__ counts, int E) {
    int e = blockIdx.x * 256 + threadIdx.x;
    if (e < E) atomicAdd(&counts[dst[e]], 1);
}

__global__ __launch_bounds__(256) void scanA_kernel(const int* __restrict__ counts,
                                                    int* __restrict__ row_start,
                                                    int* __restrict__ bsum, int n) {
    __shared__ int wt[4];
    const int t = threadIdx.x, lane = t & 63, wid = t >> 6;
    const int i = blockIdx.x * 256 + t;
    int v = (i < n) ? counts[i] : 0;
    int s = v;
    #pragma unroll
    for (int off = 1; off < 64; off <<= 1) {
        int u = __shfl_up(s, off, 64);
        if (lane >= off) s += u;
    }
    if (lane == 63) wt[wid] = s;
    __syncthreads();
    int add = 0;
    #pragma unroll
    for (int w = 0; w < 4; ++w) add += (w < wid) ? wt[w] : 0;
    s += add;
    if (i < n) row_start[i + 1] = s;
    if (t == 255) bsum[blockIdx.x] = s;
}

__global__ __launch_bounds__(256) void scanB_kernel(const int* __restrict__ bsum,
                                                    int* __restrict__ bsum2, int m) {
    __shared__ int wt[4];
    const int t = threadIdx.x, lane = t & 63, wid = t >> 6;
    int v = (t < m) ? bsum[t] : 0;
    int s = v;
    #pragma unroll
    for (int off = 1; off < 64; off <<= 1) {
        int u = __shfl_up(s, off, 64);
        if (lane >= off) s += u;
    }
    if (lane == 63) wt[wid] = s;
    __syncthreads();
    int add = 0;
    #pragma unroll
    for (int w = 0; w < 4; ++w) add += (w < wid) ? wt[w] : 0;
    s += add;
    if (t < m) bsum2[t] = s - v;   // exclusive
}

__global__ __launch_bounds__(256) void scanC_kernel(int* __restrict__ row_start,
                                                    int* __restrict__ cursor,
                                                    const int* __restrict__ bsum2, int n) {
    const int i = blockIdx.x * 256 + threadIdx.x;
    if (i == 0) { row_start[0] = 0; cursor[0] = 0; }
    if (i < n) {
        int val = row_start[i + 1] + bsum2[blockIdx.x];
        row_start[i + 1] = val;
        if (i + 1 < n) cursor[i + 1] = val;
    }
}

__global__ __launch_bounds__(256) void scatter_kernel(const int* __restrict__ src,
                                                      const int* __restrict__ dst,
                                                      const int* __restrict__ eattr,
                                                      int* __restrict__ cursor,
                                                      u16* __restrict__ esrc,
                                                      u8* __restrict__ ecode, int E) {
    int e = blockIdx.x * 256 + threadIdx.x;
    if (e < E) {
        int s = src[e];
        int code = eattr[2 * e] * 3 + eattr[2 * e + 1];
        int pos = atomicAdd(&cursor[dst[e]], 1);
        esrc[pos] = (u16)s;
        ecode[pos] = (u8)code;
    }
}

// ---------------- weight prep: fp32 in -> transposed bf16 out ----------------
__global__ __launch_bounds__(256) void transpose_kernel(const float* __restrict__ W1_0,
                                                        const float* __restrict__ W2_0,
                                                        const float* __restrict__ W1_1,
                                                        const float* __restrict__ W2_1,
                                                        u16* __restrict__ out) {
    int mat = blockIdx.y;
    const float* s = (mat == 0) ? W1_0 : (mat == 1) ? W2_0 : (mat == 2) ? W1_1 : W2_1;
    int K = (mat & 1) ? 256 : 128;
    int Nc = 384 - K;
    u16* d = out + mat * 32768;
    int idx = blockIdx.x * 256 + threadIdx.x;
    int n = idx / K, k = idx - n * K;
    d[idx] = f2bf(s[k * Nc + n]);
}

__global__ __launch_bounds__(128) void emb_kernel(const float* __restrict__ ee1_0,
                                                  const float* __restrict__ ee2_0,
                                                  const float* __restrict__ ee1_1,
                                                  const float* __restrict__ ee2_1,
                                                  float* __restrict__ emb) {
    int code = blockIdx.x;
    int layer = blockIdx.y;
    int d = threadIdx.x;
    int a0 = code / 3, a1 = code - a0 * 3;
    const float* e1 = layer ? ee1_1 : ee1_0;
    const float* e2 = layer ? ee2_1 : ee2_0;
    emb[layer * 18 * 128 + code * 128 + d] = e1[a0 * 128 + d] + e2[a1 * 128 + d];
}

// ---------------- aggregation: one wave per node, 8-way batched bf16 gather ----------------
__global__ __launch_bounds__(256) void aggregate_kernel(const u16* __restrict__ X,
                                                        const int* __restrict__ row_start,
                                                        const u16* __restrict__ esrc,
                                                        const u8* __restrict__ ecode,
                                                        const float* __restrict__ emb,
                                                        u16* __restrict__ A, int N) {
    __shared__ float semb[18 * 128];
    for (int i = threadIdx.x; i < 18 * 128; i += 256) semb[i] = emb[i];
    __syncthreads();
    const int node = blockIdx.x * 4 + (threadIdx.x >> 6);
    const int lane = threadIdx.x & 63;
    if (node >= N) return;
    const int s = row_start[node], e = row_start[node + 1];
    const float2* sem2 = (const float2*)semb;
    const u16* xl = X + lane * 2;
    float a0 = 0.f, a1 = 0.f;
    int i = s;
    for (; i + 8 <= e; i += 8) {
        unsigned xv[8];
        float2 ev[8];
        #pragma unroll
        for (int j = 0; j < 8; ++j) {
            int src = esrc[i + j];
            xv[j] = *(const unsigned*)(xl + src * D_FEAT);
        }
        #pragma unroll
        for (int j = 0; j < 8; ++j) ev[j] = sem2[(int)ecode[i + j] * 64 + lane];
        #pragma unroll
        for (int j = 0; j < 8; ++j) {
            a0 += __builtin_bit_cast(float, xv[j] << 16) + ev[j].x;
            a1 += __builtin_bit_cast(float, xv[j] & 0xFFFF0000u) + ev[j].y;
        }
    }
    for (; i < e; ++i) {
        int src = esrc[i];
        unsigned xv = *(const unsigned*)(xl + src * D_FEAT);
        float2 ev = sem2[(int)ecode[i] * 64 + lane];
        a0 += __builtin_bit_cast(float, xv << 16) + ev.x;
        a1 += __builtin_bit_cast(float, xv & 0xFFFF0000u) + ev.y;
    }
    unsigned out = (unsigned)f2bf(a0) | ((unsigned)f2bf(a1) << 16);
    *(unsigned*)(A + node * D_FEAT + lane * 2) = out;
}

// ---------------- fused MLP with LDS-staged weights ----------------
// A bf16 [M,128]; B1t [256x128] bf16; B2t [128x256] bf16; biases fp32.
// Weights staged into LDS in FRAGMENT order: chunk ((t*KB+kb)*64 | lane) holds the
// 16B fragment lane (quad,m16) needs for tile (t,kb) -> conflict-free ds_read_b128.
#define HPAD 264
template <bool RELU2, bool OUTF32>
__global__ __launch_bounds__(256, 1) void mlp_kernel(const u16* __restrict__ A,
                                                     const u16* __restrict__ B1t,
                                                     const float* __restrict__ bias1,
                                                     const u16* __restrict__ B2t,
                                                     const float* __restrict__ bias2,
                                                     void* __restrict__ C, int M) {
    __shared__ __align__(16) u16 wbuf[32768];           // 64 KB: W1t frags, then W2t frags
    __shared__ __align__(16) u16 hh[4][16][HPAD];       // 33 KB h round-trip
    const int tid = threadIdx.x;
    const int wave = tid >> 6;
    const int lane = tid & 63;
    const int m16 = lane & 15;
    const int quad = lane >> 4;

    const int row0 = blockIdx.x * 64 + wave * 16;
    const int arow = row0 + m16;
    const bool avalid = arow < M;

    // ---- stage W1t (src-linear coalesced reads, frag-ordered LDS writes) ----
    // W1t[n][k], n=t*16+m16, k=kb*32+quad*8: s-chunk: t=s>>8, kb=(s>>2)&3, quad=s&3, m16=(s>>4)&15
    {
        const uint4* src = (const uint4*)B1t;
        #pragma unroll
        for (int i = 0; i < 16; ++i) {
            int s = i * 256 + tid;
            uint4 v = src[s];
            int c = (((s >> 8) * 4 + ((s >> 2) & 3)) << 6) | ((s & 3) << 4) | ((s >> 4) & 15);
            *(uint4*)(wbuf + c * 8) = v;
        }
    }

    // prefetch A-fragments and bias1 (independent of LDS)
    s16x8 af[4];
    #pragma unroll
    for (int kb = 0; kb < 4; ++kb) af[kb] = s16x8{};
    if (avalid) {
        #pragma unroll
        for (int kb = 0; kb < 4; ++kb)
            af[kb] = *(const s16x8*)(A + arow * 128 + kb * 32 + quad * 8);
    }
    float b1v[16];
    #pragma unroll
    for (int t = 0; t < 16; ++t) b1v[t] = bias1[t * 16 + m16];

    __syncthreads();

    // ---- gemm1: h[16x256] = relu(A[16x128] @ W1 + b1) ----
    f32x4 acc[16];
    #pragma unroll
    for (int t = 0; t < 16; ++t) acc[t] = f32x4{0, 0, 0, 0};

    #pragma unroll
    for (int kb = 0; kb < 4; ++kb) {
        #pragma unroll
        for (int t = 0; t < 16; ++t) {
            s16x8 bf = *(const s16x8*)(wbuf + (((((t << 2) | kb) << 6) | lane) * 8));
            acc[t] = __builtin_amdgcn_mfma_f32_16x16x32_bf16(af[kb], bf, acc[t], 0, 0, 0);
        }
    }

    #pragma unroll
    for (int t = 0; t < 16; ++t) {
        const int col = t * 16 + m16;
        #pragma unroll
        for (int r = 0; r < 4; ++r) {
            float v = acc[t][r] + b1v[t];
            v = v > 0.f ? v : 0.f;
            hh[wave][quad * 4 + r][col] = f2bf(v);
        }
    }
    __syncthreads();

    // ---- stage W2t into the same buffer ----
    // W2t[n][k], n=t*16+m16 (t<8), k=kb*32+quad*8 (kb<8): t=s>>9, kb=(s>>2)&7, quad=s&3, m16=(s>>5)&15
    {
        const uint4* src = (const uint4*)B2t;
        #pragma unroll
        for (int i = 0; i < 16; ++i) {
            int s = i * 256 + tid;
            uint4 v = src[s];
            int c = (((s >> 9) * 8 + ((s >> 2) & 7)) << 6) | ((s & 3) << 4) | ((s >> 5) & 15);
            *(uint4*)(wbuf + c * 8) = v;
        }
    }
    float b2v[8];
    #pragma unroll
    for (int t = 0; t < 8; ++t) b2v[t] = bias2[t * 16 + m16];

    __syncthreads();

    // ---- gemm2: out[16x128] = h[16x256] @ W2 + b2 ----
    f32x4 acc2[8];
    #pragma unroll
    for (int t = 0; t < 8; ++t) acc2[t] = f32x4{0, 0, 0, 0};

    #pragma unroll
    for (int kb = 0; kb < 8; ++kb) {
        s16x8 haf = *(const s16x8*)(&hh[wave][m16][kb * 32 + quad * 8]);
        #pragma unroll
        for (int t = 0; t < 8; ++t) {
            s16x8 bf = *(const s16x8*)(wbuf + (((((t << 3) | kb) << 6) | lane) * 8));
            acc2[t] = __builtin_amdgcn_mfma_f32_16x16x32_bf16(haf, bf, acc2[t], 0, 0, 0);
        }
    }

    #pragma unroll
    for (int t = 0; t < 8; ++t) {
        const int col = t * 16 + m16;
        #pragma unroll
        for (int r = 0; r < 4; ++r) {
            const int row = row0 + quad * 4 + r;
            if (row < M) {
                float v = acc2[t][r] + b2v[t];
                if (RELU2) v = v > 0.f ? v : 0.f;
                if (OUTF32) ((float*)C)[row * 128 + col] = v;
                else        ((u16*)C)[row * 128 + col] = f2bf(v);
            }
        }
    }
}

extern "C" void kernel_launch(void* const* d_in, const int* in_sizes, int n_in,
                              void* d_out, int out_size, void* d_ws, size_t ws_size,
                              hipStream_t stream) {
    const int N = in_sizes[0] / D_FEAT;     // 50000
    const int E = in_sizes[1] / 2;          // 800000

    const float* x    = (const float*)d_in[0];
    const int* eidx   = (const int*)d_in[1];
    const int* eattr  = (const int*)d_in[2];
    const float* ee1_0 = (const float*)d_in[3];
    const float* ee2_0 = (const float*)d_in[4];
    const float* W1_0  = (const float*)d_in[5];
    const float* b1_0  = (const float*)d_in[6];
    const float* W2_0  = (const float*)d_in[7];
    const float* b2_0  = (const float*)d_in[8];
    const float* ee1_1 = (const float*)d_in[9];
    const float* ee2_1 = (const float*)d_in[10];
    const float* W1_1  = (const float*)d_in[11];
    const float* b1_1  = (const float*)d_in[12];
    const float* W2_1  = (const float*)d_in[13];
    const float* b2_1  = (const float*)d_in[14];

    // workspace (~15.88 MB)
    char* ws = (char*)d_ws;
    size_t off = 0;
    auto alloc = [&](size_t bytes) { size_t o = off; off = (off + bytes + 255) & ~(size_t)255; return o; };
    size_t o_rowstart = alloc((size_t)(N + 1) * 4);
    size_t o_cursor   = alloc((size_t)N * 4);
    size_t o_esrc     = alloc((size_t)E * 2);
    size_t o_ecode    = alloc((size_t)E);
    size_t o_bsum     = alloc(1024);
    size_t o_bsum2    = alloc(1024);
    size_t o_emb      = alloc(2 * 18 * 128 * 4);
    size_t o_wt       = alloc(4 * 32768 * 2);
    size_t o_aa       = alloc((size_t)N * D_FEAT * 2);

    int*   row_start = (int*)(ws + o_rowstart);
    int*   cursor    = (int*)(ws + o_cursor);
    u16*   esrc      = (u16*)(ws + o_esrc);
    u8*    ecode     = (u8*)(ws + o_ecode);
    int*   bsum      = (int*)(ws + o_bsum);
    int*   bsum2     = (int*)(ws + o_bsum2);
    float* emb       = (float*)(ws + o_emb);
    u16*   W1t_0     = (u16*)(ws + o_wt);
    u16*   W2t_0     = W1t_0 + 32768;
    u16*   W1t_1     = W2t_0 + 32768;
    u16*   W2t_1     = W1t_1 + 32768;
    u16*   AA        = (u16*)(ws + o_aa);

    // d_out (fp32, 25.6 MB) staging: front = X2 (bf16 L0 output), back = xb (bf16 x)
    u16* X2 = (u16*)d_out;
    u16* xb = (u16*)d_out + (size_t)N * D_FEAT;

    const int Eb = (E + 255) / 256;
    const int Nb = (N + 255) / 256;
    const int rows64 = (N + 63) / 64;             // 782
    const int aggB = (N + 3) / 4;
    const int n4 = N * D_FEAT / 4;

    tobf16_kernel<<<(n4 + 255) / 256, 256, 0, stream>>>((const float4*)x, xb, n4);

    // CSR build
    zero_kernel<<<Nb, 256, 0, stream>>>(cursor, N);
    count_kernel<<<Eb, 256, 0, stream>>>(eidx + E, cursor, E);
    scanA_kernel<<<Nb, 256, 0, stream>>>(cursor, row_start, bsum, N);
    scanB_kernel<<<1, 256, 0, stream>>>(bsum, bsum2, Nb);
    scanC_kernel<<<Nb, 256, 0, stream>>>(row_start, cursor, bsum2, N);
    scatter_kernel<<<Eb, 256, 0, stream>>>(eidx, eidx + E, eattr, cursor, esrc, ecode, E);

    // prep
    emb_kernel<<<dim3(18, 2), 128, 0, stream>>>(ee1_0, ee2_0, ee1_1, ee2_1, emb);
    transpose_kernel<<<dim3(128, 4), 256, 0, stream>>>(W1_0, W2_0, W1_1, W2_1, W1t_0);

    // layer 0: xb -> AA -> X2
    aggregate_kernel<<<aggB, 256, 0, stream>>>(xb, row_start, esrc, ecode, emb, AA, N);
    mlp_kernel<true, false><<<rows64, 256, 0, stream>>>(AA, W1t_0, b1_0, W2t_0, b2_0, X2, N);

    // layer 1: X2 -> AA -> d_out (fp32)
    aggregate_kernel<<<aggB, 256, 0, stream>>>(X2, row_start, esrc, ecode, emb + 18 * 128, AA, N);
    mlp_kernel<false, true><<<rows64, 256, 0, stream>>>(AA, W1t_1, b1_1, W2t_1, b2_1, d_out, N);
}

// Round 9
// 385.307 us; speedup vs baseline: 1.5445x; 1.0247x over previous
//
#include <hip/hip_runtime.h>

typedef __attribute__((ext_vector_type(8))) short s16x8;
typedef __attribute__((ext_vector_type(4))) float f32x4;
typedef unsigned short u16;
typedef unsigned char u8;

#define D_FEAT 128

__device__ __forceinline__ u16 f2bf(float f) {
    unsigned u = __builtin_bit_cast(unsigned, f);
    u = u + 0x7fffu + ((u >> 16) & 1u);   // RNE
    return (u16)(u >> 16);
}

// ---------------- x (fp32) -> bf16 ----------------
__global__ __launch_bounds__(256) void tobf16_kernel(const float4* __restrict__ X,
                                                     u16* __restrict__ out, int n4) {
    int i = blockIdx.x * 256 + threadIdx.x;
    if (i < n4) {
        float4 v = X[i];
        uint2 p;
        p.x = (unsigned)f2bf(v.x) | ((unsigned)f2bf(v.y) << 16);
        p.y = (unsigned)f2bf(v.z) | ((unsigned)f2bf(v.w) << 16);
        *(uint2*)(out + (size_t)i * 4) = p;
    }
}

// ---------------- CSR build ----------------
__global__ __launch_bounds__(256) void zero_kernel(int* __restrict__ p, int n) {
    int i = blockIdx.x * 256 + threadIdx.x;
    if (i < n) p[i] = 0;
}

__global__ __launch_bounds__(256) void count_kernel(const int* __restrict__ dst,
                                                    int* __restrict__ counts, int E) {
    int e = blockIdx.x * 256 + threadIdx.x;
    if (e < E) atomicAdd(&counts[dst[e]], 1);
}

__global__ __launch_bounds__(256) void scanA_kernel(const int* __restrict__ counts,
                                                    int* __restrict__ row_start,
                                                    int* __restrict__ bsum, int n) {
    __shared__ int wt[4];
    const int t = threadIdx.x, lane = t & 63, wid = t >> 6;
    const int i = blockIdx.x * 256 + t;
    int v = (i < n) ? counts[i] : 0;
    int s = v;
    #pragma unroll
    for (int off = 1; off < 64; off <<= 1) {
        int u = __shfl_up(s, off, 64);
        if (lane >= off) s += u;
    }
    if (lane == 63) wt[wid] = s;
    __syncthreads();
    int add = 0;
    #pragma unroll
    for (int w = 0; w < 4; ++w) add += (w < wid) ? wt[w] : 0;
    s += add;
    if (i < n) row_start[i + 1] = s;
    if (t == 255) bsum[blockIdx.x] = s;
}

__global__ __launch_bounds__(256) void scanB_kernel(const int* __restrict__ bsum,
                                                    int* __restrict__ bsum2, int m) {
    __shared__ int wt[4];
    const int t = threadIdx.x, lane = t & 63, wid = t >> 6;
    int v = (t < m) ? bsum[t] : 0;
    int s = v;
    #pragma unroll
    for (int off = 1; off < 64; off <<= 1) {
        int u = __shfl_up(s, off, 64);
        if (lane >= off) s += u;
    }
    if (lane == 63) wt[wid] = s;
    __syncthreads();
    int add = 0;
    #pragma unroll
    for (int w = 0; w < 4; ++w) add += (w < wid) ? wt[w] : 0;
    s += add;
    if (t < m) bsum2[t] = s - v;   // exclusive
}

__global__ __launch_bounds__(256) void scanC_kernel(int* __restrict__ row_start,
                                                    int* __restrict__ cursor,
                                                    const int* __restrict__ bsum2, int n) {
    const int i = blockIdx.x * 256 + threadIdx.x;
    if (i == 0) { row_start[0] = 0; cursor[0] = 0; }
    if (i < n) {
        int val = row_start[i + 1] + bsum2[blockIdx.x];
        row_start[i + 1] = val;
        if (i + 1 < n) cursor[i + 1] = val;
    }
}

// one random 4B store per edge: edges[pos] = src | (code<<16)
__global__ __launch_bounds__(256) void scatter_kernel(const int* __restrict__ src,
                                                      const int* __restrict__ dst,
                                                      const int* __restrict__ eattr,
                                                      int* __restrict__ cursor,
                                                      unsigned* __restrict__ edges, int E) {
    int e = blockIdx.x * 256 + threadIdx.x;
    if (e < E) {
        unsigned s = (unsigned)src[e];
        unsigned code = (unsigned)(eattr[2 * e] * 3 + eattr[2 * e + 1]);
        int pos = atomicAdd(&cursor[dst[e]], 1);
        edges[pos] = s | (code << 16);
    }
}

// ---------------- weight prep: fp32 in -> transposed bf16 out ----------------
__global__ __launch_bounds__(256) void transpose_kernel(const float* __restrict__ W1_0,
                                                        const float* __restrict__ W2_0,
                                                        const float* __restrict__ W1_1,
                                                        const float* __restrict__ W2_1,
                                                        u16* __restrict__ out) {
    int mat = blockIdx.y;
    const float* s = (mat == 0) ? W1_0 : (mat == 1) ? W2_0 : (mat == 2) ? W1_1 : W2_1;
    int K = (mat & 1) ? 256 : 128;
    int Nc = 384 - K;
    u16* d = out + mat * 32768;
    int idx = blockIdx.x * 256 + threadIdx.x;
    int n = idx / K, k = idx - n * K;
    d[idx] = f2bf(s[k * Nc + n]);
}

__global__ __launch_bounds__(128) void emb_kernel(const float* __restrict__ ee1_0,
                                                  const float* __restrict__ ee2_0,
                                                  const float* __restrict__ ee1_1,
                                                  const float* __restrict__ ee2_1,
                                                  float* __restrict__ emb) {
    int code = blockIdx.x;
    int layer = blockIdx.y;
    int d = threadIdx.x;
    int a0 = code / 3, a1 = code - a0 * 3;
    const float* e1 = layer ? ee1_1 : ee1_0;
    const float* e2 = layer ? ee2_1 : ee2_0;
    emb[layer * 18 * 128 + code * 128 + d] = e1[a0 * 128 + d] + e2[a1 * 128 + d];
}

// ---------------- aggregation: one wave per node, 8-way batched bf16 gather ----------------
__global__ __launch_bounds__(256) void aggregate_kernel(const u16* __restrict__ X,
                                                        const int* __restrict__ row_start,
                                                        const unsigned* __restrict__ edges,
                                                        const float* __restrict__ emb,
                                                        u16* __restrict__ A, int N) {
    __shared__ float semb[18 * 128];
    for (int i = threadIdx.x; i < 18 * 128; i += 256) semb[i] = emb[i];
    __syncthreads();
    const int node = blockIdx.x * 4 + (threadIdx.x >> 6);
    const int lane = threadIdx.x & 63;
    if (node >= N) return;
    const int s = row_start[node], e = row_start[node + 1];
    const float2* sem2 = (const float2*)semb;
    const u16* xl = X + lane * 2;
    float a0 = 0.f, a1 = 0.f;
    int i = s;
    for (; i + 8 <= e; i += 8) {
        unsigned xv[8];
        float2 ev[8];
        unsigned p[8];
        #pragma unroll
        for (int j = 0; j < 8; ++j) p[j] = edges[i + j];
        #pragma unroll
        for (int j = 0; j < 8; ++j)
            xv[j] = *(const unsigned*)(xl + (p[j] & 0xFFFFu) * D_FEAT);
        #pragma unroll
        for (int j = 0; j < 8; ++j) ev[j] = sem2[(int)(p[j] >> 16) * 64 + lane];
        #pragma unroll
        for (int j = 0; j < 8; ++j) {
            a0 += __builtin_bit_cast(float, xv[j] << 16) + ev[j].x;
            a1 += __builtin_bit_cast(float, xv[j] & 0xFFFF0000u) + ev[j].y;
        }
    }
    for (; i < e; ++i) {
        unsigned p = edges[i];
        unsigned xv = *(const unsigned*)(xl + (p & 0xFFFFu) * D_FEAT);
        float2 ev = sem2[(int)(p >> 16) * 64 + lane];
        a0 += __builtin_bit_cast(float, xv << 16) + ev.x;
        a1 += __builtin_bit_cast(float, xv & 0xFFFF0000u) + ev.y;
    }
    unsigned out = (unsigned)f2bf(a0) | ((unsigned)f2bf(a1) << 16);
    *(unsigned*)(A + node * D_FEAT + lane * 2) = out;
}

// ---------------- fused MLP with LDS-staged weights (round-8 verbatim) ----------------
#define HPAD 264
template <bool RELU2, bool OUTF32>
__global__ __launch_bounds__(256, 1) void mlp_kernel(const u16* __restrict__ A,
                                                     const u16* __restrict__ B1t,
                                                     const float* __restrict__ bias1,
                                                     const u16* __restrict__ B2t,
                                                     const float* __restrict__ bias2,
                                                     void* __restrict__ C, int M) {
    __shared__ __align__(16) u16 wbuf[32768];
    __shared__ __align__(16) u16 hh[4][16][HPAD];
    const int tid = threadIdx.x;
    const int wave = tid >> 6;
    const int lane = tid & 63;
    const int m16 = lane & 15;
    const int quad = lane >> 4;

    const int row0 = blockIdx.x * 64 + wave * 16;
    const int arow = row0 + m16;
    const bool avalid = arow < M;

    // stage W1t (src-linear reads, frag-ordered LDS writes)
    {
        const uint4* src = (const uint4*)B1t;
        #pragma unroll
        for (int i = 0; i < 16; ++i) {
            int s = i * 256 + tid;
            uint4 v = src[s];
            int c = (((s >> 8) * 4 + ((s >> 2) & 3)) << 6) | ((s & 3) << 4) | ((s >> 4) & 15);
            *(uint4*)(wbuf + c * 8) = v;
        }
    }

    s16x8 af[4];
    #pragma unroll
    for (int kb = 0; kb < 4; ++kb) af[kb] = s16x8{};
    if (avalid) {
        #pragma unroll
        for (int kb = 0; kb < 4; ++kb)
            af[kb] = *(const s16x8*)(A + arow * 128 + kb * 32 + quad * 8);
    }
    float b1v[16];
    #pragma unroll
    for (int t = 0; t < 16; ++t) b1v[t] = bias1[t * 16 + m16];

    __syncthreads();

    f32x4 acc[16];
    #pragma unroll
    for (int t = 0; t < 16; ++t) acc[t] = f32x4{0, 0, 0, 0};

    #pragma unroll
    for (int kb = 0; kb < 4; ++kb) {
        #pragma unroll
        for (int t = 0; t < 16; ++t) {
            s16x8 bf = *(const s16x8*)(wbuf + (((((t << 2) | kb) << 6) | lane) * 8));
            acc[t] = __builtin_amdgcn_mfma_f32_16x16x32_bf16(af[kb], bf, acc[t], 0, 0, 0);
        }
    }

    #pragma unroll
    for (int t = 0; t < 16; ++t) {
        const int col = t * 16 + m16;
        #pragma unroll
        for (int r = 0; r < 4; ++r) {
            float v = acc[t][r] + b1v[t];
            v = v > 0.f ? v : 0.f;
            hh[wave][quad * 4 + r][col] = f2bf(v);
        }
    }
    __syncthreads();

    // stage W2t
    {
        const uint4* src = (const uint4*)B2t;
        #pragma unroll
        for (int i = 0; i < 16; ++i) {
            int s = i * 256 + tid;
            uint4 v = src[s];
            int c = (((s >> 9) * 8 + ((s >> 2) & 7)) << 6) | ((s & 3) << 4) | ((s >> 5) & 15);
            *(uint4*)(wbuf + c * 8) = v;
        }
    }
    float b2v[8];
    #pragma unroll
    for (int t = 0; t < 8; ++t) b2v[t] = bias2[t * 16 + m16];

    __syncthreads();

    f32x4 acc2[8];
    #pragma unroll
    for (int t = 0; t < 8; ++t) acc2[t] = f32x4{0, 0, 0, 0};

    #pragma unroll
    for (int kb = 0; kb < 8; ++kb) {
        s16x8 haf = *(const s16x8*)(&hh[wave][m16][kb * 32 + quad * 8]);
        #pragma unroll
        for (int t = 0; t < 8; ++t) {
            s16x8 bf = *(const s16x8*)(wbuf + (((((t << 3) | kb) << 6) | lane) * 8));
            acc2[t] = __builtin_amdgcn_mfma_f32_16x16x32_bf16(haf, bf, acc2[t], 0, 0, 0);
        }
    }

    #pragma unroll
    for (int t = 0; t < 8; ++t) {
        const int col = t * 16 + m16;
        #pragma unroll
        for (int r = 0; r < 4; ++r) {
            const int row = row0 + quad * 4 + r;
            if (row < M) {
                float v = acc2[t][r] + b2v[t];
                if (RELU2) v = v > 0.f ? v : 0.f;
                if (OUTF32) ((float*)C)[row * 128 + col] = v;
                else        ((u16*)C)[row * 128 + col] = f2bf(v);
            }
        }
    }
}

extern "C" void kernel_launch(void* const* d_in, const int* in_sizes, int n_in,
                              void* d_out, int out_size, void* d_ws, size_t ws_size,
                              hipStream_t stream) {
    const int N = in_sizes[0] / D_FEAT;     // 50000
    const int E = in_sizes[1] / 2;          // 800000

    const float* x    = (const float*)d_in[0];
    const int* eidx   = (const int*)d_in[1];
    const int* eattr  = (const int*)d_in[2];
    const float* ee1_0 = (const float*)d_in[3];
    const float* ee2_0 = (const float*)d_in[4];
    const float* W1_0  = (const float*)d_in[5];
    const float* b1_0  = (const float*)d_in[6];
    const float* W2_0  = (const float*)d_in[7];
    const float* b2_0  = (const float*)d_in[8];
    const float* ee1_1 = (const float*)d_in[9];
    const float* ee2_1 = (const float*)d_in[10];
    const float* W1_1  = (const float*)d_in[11];
    const float* b1_1  = (const float*)d_in[12];
    const float* W2_1  = (const float*)d_in[13];
    const float* b2_1  = (const float*)d_in[14];

    // workspace (~16.68 MB)
    char* ws = (char*)d_ws;
    size_t off = 0;
    auto alloc = [&](size_t bytes) { size_t o = off; off = (off + bytes + 255) & ~(size_t)255; return o; };
    size_t o_rowstart = alloc((size_t)(N + 1) * 4);
    size_t o_cursor   = alloc((size_t)N * 4);
    size_t o_edges    = alloc((size_t)E * 4);
    size_t o_bsum     = alloc(1024);
    size_t o_bsum2    = alloc(1024);
    size_t o_emb      = alloc(2 * 18 * 128 * 4);
    size_t o_wt       = alloc(4 * 32768 * 2);
    size_t o_aa       = alloc((size_t)N * D_FEAT * 2);

    int*      row_start = (int*)(ws + o_rowstart);
    int*      cursor    = (int*)(ws + o_cursor);   // doubles as counts
    unsigned* edges     = (unsigned*)(ws + o_edges);
    int*      bsum      = (int*)(ws + o_bsum);
    int*      bsum2     = (int*)(ws + o_bsum2);
    float*    emb       = (float*)(ws + o_emb);
    u16*      W1t_0     = (u16*)(ws + o_wt);
    u16*      W2t_0     = W1t_0 + 32768;
    u16*      W1t_1     = W2t_0 + 32768;
    u16*      W2t_1     = W1t_1 + 32768;
    u16*      AA        = (u16*)(ws + o_aa);

    // d_out (fp32, 25.6 MB) staging: front = X2 (bf16 L0 output), back = xb (bf16 x)
    u16* X2 = (u16*)d_out;
    u16* xb = (u16*)d_out + (size_t)N * D_FEAT;

    const int Eb = (E + 255) / 256;
    const int Nb = (N + 255) / 256;
    const int rows64 = (N + 63) / 64;             // 782
    const int aggB = (N + 3) / 4;
    const int n4 = N * D_FEAT / 4;

    tobf16_kernel<<<(n4 + 255) / 256, 256, 0, stream>>>((const float4*)x, xb, n4);

    // CSR build
    zero_kernel<<<Nb, 256, 0, stream>>>(cursor, N);
    count_kernel<<<Eb, 256, 0, stream>>>(eidx + E, cursor, E);
    scanA_kernel<<<Nb, 256, 0, stream>>>(cursor, row_start, bsum, N);
    scanB_kernel<<<1, 256, 0, stream>>>(bsum, bsum2, Nb);
    scanC_kernel<<<Nb, 256, 0, stream>>>(row_start, cursor, bsum2, N);
    scatter_kernel<<<Eb, 256, 0, stream>>>(eidx, eidx + E, eattr, cursor, edges, E);

    // prep
    emb_kernel<<<dim3(18, 2), 128, 0, stream>>>(ee1_0, ee2_0, ee1_1, ee2_1, emb);
    transpose_kernel<<<dim3(128, 4), 256, 0, stream>>>(W1_0, W2_0, W1_1, W2_1, W1t_0);

    // layer 0: xb -> AA -> X2
    aggregate_kernel<<<aggB, 256, 0, stream>>>(xb, row_start, edges, emb, AA, N);
    mlp_kernel<true, false><<<rows64, 256, 0, stream>>>(AA, W1t_0, b1_0, W2t_0, b2_0, X2, N);

    // layer 1: X2 -> AA -> d_out (fp32)
    aggregate_kernel<<<aggB, 256, 0, stream>>>(X2, row_start, edges, emb + 18 * 128, AA, N);
    mlp_kernel<false, true><<<rows64, 256, 0, stream>>>(AA, W1t_1, b1_1, W2t_1, b2_1, d_out, N);
}